// Round 4
// baseline (906.944 us; speedup 1.0000x reference)
//
#include <hip/hip_runtime.h>
#include <cmath>
#include <cstdint>
#include <cstddef>

#define NB 8
#define NPTS 1024
#define BN (NB*NPTS)
#define KNN 20
#define XC_C 512
#define BN_SC 0.99999500003749973f  // 1/sqrt(1+1e-5)

static __device__ __forceinline__ float lrelu(float z) { return z >= 0.f ? z : 0.01f * z; }

static __device__ __forceinline__ unsigned long long maxu64(unsigned long long a, unsigned long long b) {
    return a > b ? a : b;
}

// DPP-based max step on a (lo,hi) u64 — VERBATIM from the R2 kernel that passed on HW.
// CTRL: row_ror:1/2/4/8 = 0x121/0x122/0x124/0x128, row_bcast15=0x142, row_bcast31=0x143.
// bound_ctrl=false + old=0 -> lanes with no source contribute 0 (= -inf sentinel).
// After the 6-step chain, lane 63 holds the wave max.
template<int CTRL>
static __device__ __forceinline__ void dpp_max(unsigned& lo, unsigned& hi) {
    unsigned tlo = (unsigned)__builtin_amdgcn_update_dpp(0, (int)lo, CTRL, 0xF, 0xF, false);
    unsigned thi = (unsigned)__builtin_amdgcn_update_dpp(0, (int)hi, CTRL, 0xF, 0xF, false);
    unsigned long long a = ((unsigned long long)hi << 32) | lo;
    unsigned long long b = ((unsigned long long)thi << 32) | tlo;
    if (b > a) { lo = tlo; hi = thi; }
}

static __device__ __forceinline__ unsigned long long wave_max_u64(unsigned long long v) {
    unsigned lo = (unsigned)v, hi = (unsigned)(v >> 32);
    dpp_max<0x121>(lo, hi);
    dpp_max<0x122>(lo, hi);
    dpp_max<0x124>(lo, hi);
    dpp_max<0x128>(lo, hi);
    dpp_max<0x142>(lo, hi);   // row_bcast15
    dpp_max<0x143>(lo, hi);   // row_bcast31; lane63 = wave max
    unsigned wlo = (unsigned)__builtin_amdgcn_readlane((int)lo, 63);
    unsigned whi = (unsigned)__builtin_amdgcn_readlane((int)hi, 63);
    return ((unsigned long long)whi << 32) | wlo;
}

// ---- prep: x (B,N,3) -> ft (B,3,N) + norms ----
__global__ void prep_k(const float* __restrict__ x, float* __restrict__ ft, float* __restrict__ nrm) {
    int i = blockIdx.x * 256 + threadIdx.x;   // b*N+n
    if (i >= BN) return;
    int b = i >> 10, n = i & 1023;
    float a = x[3*i], c = x[3*i+1], d = x[3*i+2];
    float* fb = ft + (size_t)b * 3 * NPTS;
    fb[n] = a; fb[NPTS + n] = c; fb[2*NPTS + n] = d;
    nrm[i] = a*a + c*c + d*d;
}

// ---- fused knn, two-phase: one block (4 waves) per row n.
// Phase 1: wave w owns columns [w*256, w*256+256) = 4 keys/lane; pops its local top-20
//          with the R2-proven round structure (tree-max + u64 DPP wave-max + equality sweep).
// Phase 2: wave 0 pops top-20 of the 80 candidates (2 keys/lane, same proven structure).
// Keys: hi = order-preserving u32 of (2*inner - xx[m]) (row-constant shift keeps jax order+ties),
//       lo = 1023-m  => u64-descending pop == (value desc, m asc) == jax top_k order.
template<int C>
__global__ __launch_bounds__(256) void knn_k(const float* __restrict__ ft,
                                             const float* __restrict__ frow, int frs,
                                             const float* __restrict__ nrm,
                                             int* __restrict__ idx) {
    int r = blockIdx.x;
    int w = threadIdx.x >> 6;
    int lane = threadIdx.x & 63;
    int b = r >> 10;
    const float* ftb = ft + (size_t)b * C * NPTS;
    int col4 = 64 * w + lane;            // float4 index into the 1024-wide row

    float4 acc = make_float4(0.f, 0.f, 0.f, 0.f);
    if constexpr ((C & 3) == 0) {
        const float4* cr = (const float4*)(frow + (size_t)r * frs);
        for (int c4 = 0; c4 < C/4; c4++) {
            float4 ct4 = cr[c4];
#pragma unroll
            for (int cc = 0; cc < 4; cc++) {
                float ctr = (&ct4.x)[cc];
                float4 v = ((const float4*)(ftb + (size_t)(4*c4+cc) * NPTS))[col4];
                acc.x = fmaf(ctr, v.x, acc.x);
                acc.y = fmaf(ctr, v.y, acc.y);
                acc.z = fmaf(ctr, v.z, acc.z);
                acc.w = fmaf(ctr, v.w, acc.w);
            }
        }
    } else {
        for (int c = 0; c < C; c++) {
            float ctr = frow[(size_t)r * frs + c];
            float4 v = ((const float4*)(ftb + (size_t)c * NPTS))[col4];
            acc.x = fmaf(ctr, v.x, acc.x);
            acc.y = fmaf(ctr, v.y, acc.y);
            acc.z = fmaf(ctr, v.z, acc.z);
            acc.w = fmaf(ctr, v.w, acc.w);
        }
    }

    unsigned long long key[4];
    {
        float4 nm = ((const float4*)(nrm + b * NPTS))[col4];
#pragma unroll
        for (int q = 0; q < 4; q++) {
            float f = 2.f * (&acc.x)[q] - (&nm.x)[q];
            unsigned u = __float_as_uint(f);
            unsigned s = (unsigned)((int)u >> 31);
            u ^= (s | 0x80000000u);
            int m = 4*col4 + q;
            key[q] = ((unsigned long long)u << 32) | (unsigned)(1023 - m);
        }
    }

    __shared__ unsigned long long cbuf[4 * KNN];

    // phase 1: per-wave top-20
    for (int kk = 0; kk < KNN; kk++) {
        unsigned long long best = maxu64(maxu64(key[0], key[1]), maxu64(key[2], key[3]));
        unsigned long long win = wave_max_u64(best);
        if (lane == 0) cbuf[w * KNN + kk] = win;
#pragma unroll
        for (int t = 0; t < 4; t++) key[t] = (key[t] == win) ? 0ull : key[t];
    }
    __syncthreads();

    // phase 2: wave 0 merges 80 candidates (u64 keys globally unique)
    if (w == 0) {
        unsigned long long k2[2];
        k2[0] = cbuf[lane];
        k2[1] = (lane < 4 * KNN - 64) ? cbuf[64 + lane] : 0ull;
        int mine = 0;
        for (int kk = 0; kk < KNN; kk++) {
            unsigned long long win = wave_max_u64(maxu64(k2[0], k2[1]));
            int m = 1023 - (int)(unsigned)win;
            if (lane == kk) mine = m;
            k2[0] = (k2[0] == win) ? 0ull : k2[0];
            k2[1] = (k2[1] == win) ? 0ull : k2[1];
        }
        if (lane < KNN) idx[r * KNN + lane] = mine;
    }
}

// ---- H/Ct GEMM: Ht[n,o]=F.w1; Ct[n,o]=F.w2 - Ht + bias ----
// grid BN/4, block O; 4 rows per block for w-reuse.
template<int C, int O, bool HASB>
__global__ void hc_k(const float* __restrict__ F, int FS,
                     const float* __restrict__ w, const float* __restrict__ bias,
                     float* __restrict__ Ht, float* __restrict__ Ct) {
    int r0 = blockIdx.x * 4;
    int o = threadIdx.x;
    const float* wr = w + (size_t)o * (2*C);
    float h[4] = {0,0,0,0}, a2[4] = {0,0,0,0};
    if constexpr ((C & 3) == 0) {
        const float4* w1 = (const float4*)wr;
        const float4* w2 = (const float4*)(wr + C);
#pragma unroll 4
        for (int c4 = 0; c4 < C/4; c4++) {
            float4 wa = w1[c4], wb = w2[c4];
#pragma unroll
            for (int nn = 0; nn < 4; nn++) {
                float4 f = *(const float4*)(F + (size_t)(r0+nn)*FS + 4*c4);  // broadcast
                h[nn]  = fmaf(wa.x,f.x, fmaf(wa.y,f.y, fmaf(wa.z,f.z, fmaf(wa.w,f.w, h[nn]))));
                a2[nn] = fmaf(wb.x,f.x, fmaf(wb.y,f.y, fmaf(wb.z,f.z, fmaf(wb.w,f.w, a2[nn]))));
            }
        }
    } else {
        for (int c = 0; c < C; c++) {
            float wa = wr[c], wb = wr[C+c];
#pragma unroll
            for (int nn = 0; nn < 4; nn++) {
                float f = F[(size_t)(r0+nn)*FS + c];
                h[nn]  = fmaf(wa, f, h[nn]);
                a2[nn] = fmaf(wb, f, a2[nn]);
            }
        }
    }
    float bs = 0.f;
    if constexpr (HASB) bs = bias[o];
#pragma unroll
    for (int nn = 0; nn < 4; nn++) {
        size_t ro = (size_t)(r0+nn)*O + o;
        Ht[ro] = h[nn];
        Ct[ro] = a2[nn] - h[nn] + bs;
    }
}

// ---- gather + max_k + bn + lrelu; optional transposed-feature + norms for next knn ----
template<int O, bool WFT>
__global__ void gmax_k(const float* __restrict__ Ht, const float* __restrict__ Ct,
                       const int* __restrict__ idx,
                       const float* __restrict__ g, const float* __restrict__ bb,
                       float* __restrict__ xcs, float* __restrict__ ft, float* __restrict__ nrm) {
    int r = blockIdx.x;
    int b = r >> 10, n = r & 1023;
    int o = threadIdx.x;
    const int* id = idx + r * KNN;
    float vmax = -INFINITY, vmin = INFINITY;
    const float* hb = Ht + (size_t)b * NPTS * O + o;
#pragma unroll 4
    for (int k = 0; k < KNN; k++) {
        int m = id[k];                 // broadcast
        float v = hb[(size_t)m * O];   // coalesced across o
        vmax = fmaxf(vmax, v); vmin = fminf(vmin, v);
    }
    float ct = Ct[(size_t)r * O + o];
    float s = g[o] * BN_SC;
    float pre = (s >= 0.f ? vmax : vmin) + ct;
    float out = lrelu(fmaf(s, pre, bb[o]));
    xcs[(size_t)r * XC_C + o] = out;
    if constexpr (WFT) {
        ft[((size_t)b * O + o) * NPTS + n] = out;
        float sq = out * out;
#pragma unroll
        for (int off = 32; off > 0; off >>= 1) sq += __shfl_xor(sq, off);
        __shared__ float red[O/64 > 0 ? O/64 : 1];
        if ((o & 63) == 0) red[o >> 6] = sq;
        __syncthreads();
        if (o == 0) {
            float t = 0.f;
#pragma unroll
            for (int i = 0; i < O/64; i++) t += red[i];
            nrm[r] = t;
        }
    }
}

// ---- w5 transpose (1024,512) -> (512,1024) for coalesced o-loads ----
__global__ void w5t_k(const float* __restrict__ w5, float* __restrict__ w5t) {
    int i = blockIdx.x * 256 + threadIdx.x;   // c*1024+o
    int c = i >> 10, o = i & 1023;
    w5t[i] = w5[(size_t)o * 512 + c];
}

// ---- conv5 + partial max over n: grid (64 ntiles, B), block 256; thread = 4 o, 16 n ----
__global__ __launch_bounds__(256) void conv5max_k(const float* __restrict__ xc,
                                                  const float* __restrict__ w5t,
                                                  float* __restrict__ part) {
    int b = blockIdx.y, nt = blockIdx.x;
    int o4 = threadIdx.x;
    const float* xb = xc + ((size_t)b * NPTS + nt * 16) * XC_C;
    float4 acc[16];
#pragma unroll
    for (int i = 0; i < 16; i++) acc[i] = make_float4(0.f,0.f,0.f,0.f);
    for (int c = 0; c < 512; c++) {
        float4 w4 = ((const float4*)(w5t + (size_t)c * 1024))[o4];  // coalesced
#pragma unroll
        for (int nn = 0; nn < 16; nn++) {
            float xv = xb[(size_t)nn * XC_C + c];                   // uniform -> scalar path
            acc[nn].x = fmaf(w4.x, xv, acc[nn].x);
            acc[nn].y = fmaf(w4.y, xv, acc[nn].y);
            acc[nn].z = fmaf(w4.z, xv, acc[nn].z);
            acc[nn].w = fmaf(w4.w, xv, acc[nn].w);
        }
    }
    float4 m = acc[0];
#pragma unroll
    for (int nn = 1; nn < 16; nn++) {
        m.x = fmaxf(m.x, acc[nn].x); m.y = fmaxf(m.y, acc[nn].y);
        m.z = fmaxf(m.z, acc[nn].z); m.w = fmaxf(m.w, acc[nn].w);
    }
    ((float4*)(part + ((size_t)b * 64 + nt) * 1024))[o4] = m;
}

// ---- head: reduce partials -> gpool -> lin1/bn6/lrelu -> lin2/bn7/lrelu -> lin3 ----
__global__ __launch_bounds__(256) void head_k(const float* __restrict__ part,
        const float* __restrict__ l1w, const float* __restrict__ g6, const float* __restrict__ b6,
        const float* __restrict__ l2w, const float* __restrict__ l2b,
        const float* __restrict__ g7, const float* __restrict__ b7,
        const float* __restrict__ l3w, const float* __restrict__ l3b,
        float* __restrict__ out) {
    int b = blockIdx.x, t = threadIdx.x;
    __shared__ float gp[1024];
    __shared__ float y1[512];
    __shared__ float y2[256];
    const float* pb = part + (size_t)b * 64 * 1024;
    for (int o = t; o < 1024; o += 256) {
        float m = pb[o];
        for (int j = 1; j < 64; j++) m = fmaxf(m, pb[(size_t)j * 1024 + o]);
        gp[o] = m;
    }
    __syncthreads();
    for (int j = t; j < 512; j += 256) {
        const float4* wr = (const float4*)(l1w + (size_t)j * 1024);
        const float4* g4 = (const float4*)gp;
        float acc = 0.f;
        for (int c = 0; c < 256; c++) {
            float4 w = wr[c], x = g4[c];
            acc = fmaf(w.x,x.x, fmaf(w.y,x.y, fmaf(w.z,x.z, fmaf(w.w,x.w, acc))));
        }
        y1[j] = lrelu(fmaf(acc, g6[j] * BN_SC, b6[j]));
    }
    __syncthreads();
    {
        const float4* wr = (const float4*)(l2w + (size_t)t * 512);
        const float4* y4 = (const float4*)y1;
        float acc = l2b[t];
        for (int c = 0; c < 128; c++) {
            float4 w = wr[c], x = y4[c];
            acc = fmaf(w.x,x.x, fmaf(w.y,x.y, fmaf(w.z,x.z, fmaf(w.w,x.w, acc))));
        }
        y2[t] = lrelu(fmaf(acc, g7[t] * BN_SC, b7[t]));
    }
    __syncthreads();
    if (t < 40) {
        const float4* wr = (const float4*)(l3w + (size_t)t * 256);
        const float4* y4 = (const float4*)y2;
        float acc = l3b[t];
        for (int c = 0; c < 64; c++) {
            float4 w = wr[c], x = y4[c];
            acc = fmaf(w.x,x.x, fmaf(w.y,x.y, fmaf(w.z,x.z, fmaf(w.w,x.w, acc))));
        }
        out[b * 40 + t] = acc;
    }
}

extern "C" void kernel_launch(void* const* d_in, const int* in_sizes, int n_in,
                              void* d_out, int out_size, void* d_ws, size_t ws_size,
                              hipStream_t stream) {
    const float* x       = (const float*)d_in[0];
    const float* conv1_w = (const float*)d_in[1];
    const float* conv1_b = (const float*)d_in[2];
    const float* bn1_g   = (const float*)d_in[3];
    const float* bn1_b   = (const float*)d_in[4];
    const float* conv2_w = (const float*)d_in[5];
    const float* bn2_g   = (const float*)d_in[6];
    const float* bn2_b   = (const float*)d_in[7];
    const float* conv3_w = (const float*)d_in[8];
    const float* bn3_g   = (const float*)d_in[9];
    const float* bn3_b   = (const float*)d_in[10];
    const float* conv4_w = (const float*)d_in[11];
    const float* bn4_g   = (const float*)d_in[12];
    const float* bn4_b   = (const float*)d_in[13];
    const float* conv5_w = (const float*)d_in[14];
    const float* lin1_w  = (const float*)d_in[15];
    const float* bn6_g   = (const float*)d_in[16];
    const float* bn6_b   = (const float*)d_in[17];
    const float* lin2_w  = (const float*)d_in[18];
    const float* lin2_b  = (const float*)d_in[19];
    const float* bn7_g   = (const float*)d_in[20];
    const float* bn7_b   = (const float*)d_in[21];
    const float* lin3_w  = (const float*)d_in[22];
    const float* lin3_b  = (const float*)d_in[23];
    float* outp = (float*)d_out;

    // workspace layout (floats): total 10,657,792 f = 42.6 MB
    float* ws   = (float*)d_ws;
    float* xc   = ws;                          // (BN,512)          4,194,304
    int*   idxb = (int*)(ws + 4194304);        // (BN,20)             163,840
    float* nrm  = ws + 4194304 + 163840;       // (BN)                  8,192
    float* ft   = nrm + 8192;                  // (B,<=128,N)       1,048,576
    float* part = ft + 1048576;                // (B,64,1024)         524,288
    float* w5t  = part + 524288;               // (512,1024)          524,288
    float* Ht   = w5t + 524288;                // (BN,<=256)        2,097,152
    float* Ct   = Ht + 2097152;                // (BN,<=256)        2,097,152

    prep_k<<<BN/256, 256, 0, stream>>>(x, ft, nrm);

    // Stage 1: C=3 (coords), O=64, with conv bias
    knn_k<3><<<BN, 256, 0, stream>>>(ft, x, 3, nrm, idxb);
    hc_k<3, 64, true><<<BN/4, 64, 0, stream>>>(x, 3, conv1_w, conv1_b, Ht, Ct);
    gmax_k<64, true><<<BN, 64, 0, stream>>>(Ht, Ct, idxb, bn1_g, bn1_b, xc + 0, ft, nrm);

    // Stage 2: C=64 -> O=64
    knn_k<64><<<BN, 256, 0, stream>>>(ft, xc + 0, XC_C, nrm, idxb);
    hc_k<64, 64, false><<<BN/4, 64, 0, stream>>>(xc + 0, XC_C, conv2_w, nullptr, Ht, Ct);
    gmax_k<64, true><<<BN, 64, 0, stream>>>(Ht, Ct, idxb, bn2_g, bn2_b, xc + 64, ft, nrm);

    // Stage 3: C=64 -> O=128
    knn_k<64><<<BN, 256, 0, stream>>>(ft, xc + 64, XC_C, nrm, idxb);
    hc_k<64, 128, false><<<BN/4, 128, 0, stream>>>(xc + 64, XC_C, conv3_w, nullptr, Ht, Ct);
    gmax_k<128, true><<<BN, 128, 0, stream>>>(Ht, Ct, idxb, bn3_g, bn3_b, xc + 128, ft, nrm);

    // Stage 4: C=128 -> O=256 (no next knn)
    knn_k<128><<<BN, 256, 0, stream>>>(ft, xc + 128, XC_C, nrm, idxb);
    hc_k<128, 256, false><<<BN/4, 256, 0, stream>>>(xc + 128, XC_C, conv4_w, nullptr, Ht, Ct);
    gmax_k<256, false><<<BN, 256, 0, stream>>>(Ht, Ct, idxb, bn4_g, bn4_b, xc + 256, nullptr, nullptr);

    // conv5 + global max pool + head
    w5t_k<<<(512*1024)/256, 256, 0, stream>>>(conv5_w, w5t);
    conv5max_k<<<dim3(64, NB), 256, 0, stream>>>(xc, w5t, part);
    head_k<<<NB, 256, 0, stream>>>(part, lin1_w, bn6_g, bn6_b, lin2_w, lin2_b,
                                   bn7_g, bn7_b, lin3_w, lin3_b, outp);
}

// Round 5
// 761.478 us; speedup vs baseline: 1.1910x; 1.1910x over previous
//
#include <hip/hip_runtime.h>
#include <cmath>
#include <cstdint>
#include <cstddef>

#define NB 8
#define NPTS 1024
#define BN (NB*NPTS)
#define KNN 20
#define XC_C 512
#define BN_SC 0.99999500003749973f  // 1/sqrt(1+1e-5)

static __device__ __forceinline__ float lrelu(float z) { return z >= 0.f ? z : 0.01f * z; }

static __device__ __forceinline__ unsigned long long maxu64(unsigned long long a, unsigned long long b) {
    return a > b ? a : b;
}

// Interleaved DPP max step for TWO independent (lo,hi) u64 chains — same semantics as the
// R2-validated dpp_max, issued pairwise so the two dependent chains overlap.
// CTRL: row_ror:1/2/4/8 = 0x121/0x122/0x124/0x128, row_bcast15=0x142, row_bcast31=0x143.
// bound_ctrl=false + old=0 -> lanes with no source contribute 0 (= -inf sentinel).
template<int CTRL>
static __device__ __forceinline__ void dpp_max2(unsigned& loA, unsigned& hiA,
                                                unsigned& loB, unsigned& hiB) {
    unsigned tlA = (unsigned)__builtin_amdgcn_update_dpp(0, (int)loA, CTRL, 0xF, 0xF, false);
    unsigned thA = (unsigned)__builtin_amdgcn_update_dpp(0, (int)hiA, CTRL, 0xF, 0xF, false);
    unsigned tlB = (unsigned)__builtin_amdgcn_update_dpp(0, (int)loB, CTRL, 0xF, 0xF, false);
    unsigned thB = (unsigned)__builtin_amdgcn_update_dpp(0, (int)hiB, CTRL, 0xF, 0xF, false);
    unsigned long long a = ((unsigned long long)hiA << 32) | loA;
    unsigned long long b = ((unsigned long long)thA << 32) | tlA;
    if (b > a) { loA = tlA; hiA = thA; }
    unsigned long long c = ((unsigned long long)hiB << 32) | loB;
    unsigned long long d = ((unsigned long long)thB << 32) | tlB;
    if (d > c) { loB = tlB; hiB = thB; }
}

// Two interleaved wave-max chains; after the chain lane 63 holds each wave max (R2-validated pattern).
static __device__ __forceinline__ void wave_max_u64_x2(unsigned long long vA, unsigned long long vB,
                                                       unsigned long long& winA, unsigned long long& winB) {
    unsigned loA = (unsigned)vA, hiA = (unsigned)(vA >> 32);
    unsigned loB = (unsigned)vB, hiB = (unsigned)(vB >> 32);
    dpp_max2<0x121>(loA, hiA, loB, hiB);
    dpp_max2<0x122>(loA, hiA, loB, hiB);
    dpp_max2<0x124>(loA, hiA, loB, hiB);
    dpp_max2<0x128>(loA, hiA, loB, hiB);
    dpp_max2<0x142>(loA, hiA, loB, hiB);   // row_bcast15
    dpp_max2<0x143>(loA, hiA, loB, hiB);   // row_bcast31; lane63 = wave max
    unsigned wloA = (unsigned)__builtin_amdgcn_readlane((int)loA, 63);
    unsigned whiA = (unsigned)__builtin_amdgcn_readlane((int)hiA, 63);
    unsigned wloB = (unsigned)__builtin_amdgcn_readlane((int)loB, 63);
    unsigned whiB = (unsigned)__builtin_amdgcn_readlane((int)hiB, 63);
    winA = ((unsigned long long)whiA << 32) | wloA;
    winB = ((unsigned long long)whiB << 32) | wloB;
}

// ---- prep: x (B,N,3) -> ft (B,3,N) + norms ----
__global__ void prep_k(const float* __restrict__ x, float* __restrict__ ft, float* __restrict__ nrm) {
    int i = blockIdx.x * 256 + threadIdx.x;   // b*N+n
    if (i >= BN) return;
    int b = i >> 10, n = i & 1023;
    float a = x[3*i], c = x[3*i+1], d = x[3*i+2];
    float* fb = ft + (size_t)b * 3 * NPTS;
    fb[n] = a; fb[NPTS + n] = c; fb[2*NPTS + n] = d;
    nrm[i] = a*a + c*c + d*d;
}

// ---- fused knn: R2 semantics, TWO rows per wave (interleaved chains for ILP).
// Keys: hi = order-preserving u32 of (2*inner - xx[m]) (row-constant shift keeps jax order+ties),
//       lo = 1023-m  => u64-descending pop == (value desc, m asc) == jax top_k order.
// grid BN/8 blocks x 256 threads; wave w handles rows base+2w and base+2w+1.
template<int C>
__global__ __launch_bounds__(256) void knn_k(const float* __restrict__ ft,
                                             const float* __restrict__ frow, int frs,
                                             const float* __restrict__ nrm,
                                             int* __restrict__ idx) {
    int w = threadIdx.x >> 6;
    int lane = threadIdx.x & 63;
    int rA = blockIdx.x * 8 + 2 * w;
    int rB = rA + 1;
    int b = rA >> 10;                       // same batch for both rows (8 | 1024)
    const float* ftb = ft + (size_t)b * C * NPTS;

    float4 accA[4], accB[4];
#pragma unroll
    for (int j = 0; j < 4; j++) { accA[j] = make_float4(0.f,0.f,0.f,0.f); accB[j] = make_float4(0.f,0.f,0.f,0.f); }

    if constexpr ((C & 3) == 0) {
        const float4* crA = (const float4*)(frow + (size_t)rA * frs);
        const float4* crB = (const float4*)(frow + (size_t)rB * frs);
        for (int c4 = 0; c4 < C/4; c4++) {
            float4 ctA = crA[c4], ctB = crB[c4];
#pragma unroll
            for (int cc = 0; cc < 4; cc++) {
                float cA = (&ctA.x)[cc], cB = (&ctB.x)[cc];
                const float4* rm = (const float4*)(ftb + (size_t)(4*c4+cc) * NPTS);
#pragma unroll
                for (int j = 0; j < 4; j++) {
                    float4 v = rm[lane + 64*j];          // shared m-stream for both rows
                    accA[j].x = fmaf(cA, v.x, accA[j].x);
                    accA[j].y = fmaf(cA, v.y, accA[j].y);
                    accA[j].z = fmaf(cA, v.z, accA[j].z);
                    accA[j].w = fmaf(cA, v.w, accA[j].w);
                    accB[j].x = fmaf(cB, v.x, accB[j].x);
                    accB[j].y = fmaf(cB, v.y, accB[j].y);
                    accB[j].z = fmaf(cB, v.z, accB[j].z);
                    accB[j].w = fmaf(cB, v.w, accB[j].w);
                }
            }
        }
    } else {
        for (int c = 0; c < C; c++) {
            float cA = frow[(size_t)rA * frs + c];
            float cB = frow[(size_t)rB * frs + c];
            const float4* rm = (const float4*)(ftb + (size_t)c * NPTS);
#pragma unroll
            for (int j = 0; j < 4; j++) {
                float4 v = rm[lane + 64*j];
                accA[j].x = fmaf(cA, v.x, accA[j].x);
                accA[j].y = fmaf(cA, v.y, accA[j].y);
                accA[j].z = fmaf(cA, v.z, accA[j].z);
                accA[j].w = fmaf(cA, v.w, accA[j].w);
                accB[j].x = fmaf(cB, v.x, accB[j].x);
                accB[j].y = fmaf(cB, v.y, accB[j].y);
                accB[j].z = fmaf(cB, v.z, accB[j].z);
                accB[j].w = fmaf(cB, v.w, accB[j].w);
            }
        }
    }

    unsigned long long keyA[16], keyB[16];
    const float4* nm4 = (const float4*)(nrm + b * NPTS);
#pragma unroll
    for (int j = 0; j < 4; j++) {
        float4 nm = nm4[lane + 64*j];                    // shared for both rows
#pragma unroll
        for (int q = 0; q < 4; q++) {
            int m = 4*(lane + 64*j) + q;
            float fA = 2.f * (&accA[j].x)[q] - (&nm.x)[q];
            unsigned uA = __float_as_uint(fA);
            unsigned sA = (unsigned)((int)uA >> 31);
            uA ^= (sA | 0x80000000u);
            keyA[4*j+q] = ((unsigned long long)uA << 32) | (unsigned)(1023 - m);
            float fB = 2.f * (&accB[j].x)[q] - (&nm.x)[q];
            unsigned uB = __float_as_uint(fB);
            unsigned sB = (unsigned)((int)uB >> 31);
            uB ^= (sB | 0x80000000u);
            keyB[4*j+q] = ((unsigned long long)uB << 32) | (unsigned)(1023 - m);
        }
    }

    int mineA = 0, mineB = 0;
    for (int kk = 0; kk < KNN; kk++) {
        // balanced local max-trees (interleaved A/B for ILP)
        unsigned long long a01 = maxu64(keyA[0], keyA[1]),  b01 = maxu64(keyB[0], keyB[1]);
        unsigned long long a23 = maxu64(keyA[2], keyA[3]),  b23 = maxu64(keyB[2], keyB[3]);
        unsigned long long a45 = maxu64(keyA[4], keyA[5]),  b45 = maxu64(keyB[4], keyB[5]);
        unsigned long long a67 = maxu64(keyA[6], keyA[7]),  b67 = maxu64(keyB[6], keyB[7]);
        unsigned long long a89 = maxu64(keyA[8], keyA[9]),  b89 = maxu64(keyB[8], keyB[9]);
        unsigned long long aab = maxu64(keyA[10], keyA[11]), bab = maxu64(keyB[10], keyB[11]);
        unsigned long long acd = maxu64(keyA[12], keyA[13]), bcd = maxu64(keyB[12], keyB[13]);
        unsigned long long aef = maxu64(keyA[14], keyA[15]), bef = maxu64(keyB[14], keyB[15]);
        unsigned long long aq0 = maxu64(a01, a23), bq0 = maxu64(b01, b23);
        unsigned long long aq1 = maxu64(a45, a67), bq1 = maxu64(b45, b67);
        unsigned long long aq2 = maxu64(a89, aab), bq2 = maxu64(b89, bab);
        unsigned long long aq3 = maxu64(acd, aef), bq3 = maxu64(bcd, bef);
        unsigned long long bestA = maxu64(maxu64(aq0, aq1), maxu64(aq2, aq3));
        unsigned long long bestB = maxu64(maxu64(bq0, bq1), maxu64(bq2, bq3));
        unsigned long long winA, winB;
        wave_max_u64_x2(bestA, bestB, winA, winB);
        if (lane == kk) {
            mineA = 1023 - (int)(unsigned)winA;
            mineB = 1023 - (int)(unsigned)winB;
        }
        // invalidate winners (u64 keys unique per row; 0 unreachable => safe sentinel)
#pragma unroll
        for (int t = 0; t < 16; t++) {
            keyA[t] = (keyA[t] == winA) ? 0ull : keyA[t];
            keyB[t] = (keyB[t] == winB) ? 0ull : keyB[t];
        }
    }
    if (lane < KNN) {
        idx[rA * KNN + lane] = mineA;
        idx[rB * KNN + lane] = mineB;
    }
}

// ---- H/Ct GEMM: Ht[n,o]=F.w1; Ct[n,o]=F.w2 - Ht + bias ----
// grid BN/4, block O; 4 rows per block for w-reuse.
template<int C, int O, bool HASB>
__global__ void hc_k(const float* __restrict__ F, int FS,
                     const float* __restrict__ w, const float* __restrict__ bias,
                     float* __restrict__ Ht, float* __restrict__ Ct) {
    int r0 = blockIdx.x * 4;
    int o = threadIdx.x;
    const float* wr = w + (size_t)o * (2*C);
    float h[4] = {0,0,0,0}, a2[4] = {0,0,0,0};
    if constexpr ((C & 3) == 0) {
        const float4* w1 = (const float4*)wr;
        const float4* w2 = (const float4*)(wr + C);
#pragma unroll 4
        for (int c4 = 0; c4 < C/4; c4++) {
            float4 wa = w1[c4], wb = w2[c4];
#pragma unroll
            for (int nn = 0; nn < 4; nn++) {
                float4 f = *(const float4*)(F + (size_t)(r0+nn)*FS + 4*c4);  // broadcast
                h[nn]  = fmaf(wa.x,f.x, fmaf(wa.y,f.y, fmaf(wa.z,f.z, fmaf(wa.w,f.w, h[nn]))));
                a2[nn] = fmaf(wb.x,f.x, fmaf(wb.y,f.y, fmaf(wb.z,f.z, fmaf(wb.w,f.w, a2[nn]))));
            }
        }
    } else {
        for (int c = 0; c < C; c++) {
            float wa = wr[c], wb = wr[C+c];
#pragma unroll
            for (int nn = 0; nn < 4; nn++) {
                float f = F[(size_t)(r0+nn)*FS + c];
                h[nn]  = fmaf(wa, f, h[nn]);
                a2[nn] = fmaf(wb, f, a2[nn]);
            }
        }
    }
    float bs = 0.f;
    if constexpr (HASB) bs = bias[o];
#pragma unroll
    for (int nn = 0; nn < 4; nn++) {
        size_t ro = (size_t)(r0+nn)*O + o;
        Ht[ro] = h[nn];
        Ct[ro] = a2[nn] - h[nn] + bs;
    }
}

// ---- gather + max_k + bn + lrelu; optional transposed-feature + norms for next knn ----
template<int O, bool WFT>
__global__ void gmax_k(const float* __restrict__ Ht, const float* __restrict__ Ct,
                       const int* __restrict__ idx,
                       const float* __restrict__ g, const float* __restrict__ bb,
                       float* __restrict__ xcs, float* __restrict__ ft, float* __restrict__ nrm) {
    int r = blockIdx.x;
    int b = r >> 10, n = r & 1023;
    int o = threadIdx.x;
    const int* id = idx + r * KNN;
    float vmax = -INFINITY, vmin = INFINITY;
    const float* hb = Ht + (size_t)b * NPTS * O + o;
#pragma unroll 4
    for (int k = 0; k < KNN; k++) {
        int m = id[k];                 // broadcast
        float v = hb[(size_t)m * O];   // coalesced across o
        vmax = fmaxf(vmax, v); vmin = fminf(vmin, v);
    }
    float ct = Ct[(size_t)r * O + o];
    float s = g[o] * BN_SC;
    float pre = (s >= 0.f ? vmax : vmin) + ct;
    float out = lrelu(fmaf(s, pre, bb[o]));
    xcs[(size_t)r * XC_C + o] = out;
    if constexpr (WFT) {
        ft[((size_t)b * O + o) * NPTS + n] = out;
        float sq = out * out;
#pragma unroll
        for (int off = 32; off > 0; off >>= 1) sq += __shfl_xor(sq, off);
        __shared__ float red[O/64 > 0 ? O/64 : 1];
        if ((o & 63) == 0) red[o >> 6] = sq;
        __syncthreads();
        if (o == 0) {
            float t = 0.f;
#pragma unroll
            for (int i = 0; i < O/64; i++) t += red[i];
            nrm[r] = t;
        }
    }
}

// ---- w5 transpose (1024,512) -> (512,1024) for coalesced o-loads ----
__global__ void w5t_k(const float* __restrict__ w5, float* __restrict__ w5t) {
    int i = blockIdx.x * 256 + threadIdx.x;   // c*1024+o
    int c = i >> 10, o = i & 1023;
    w5t[i] = w5[(size_t)o * 512 + c];
}

// ---- conv5 + partial max over n: grid (64 ntiles, B), block 256; thread = 4 o, 16 n ----
__global__ __launch_bounds__(256) void conv5max_k(const float* __restrict__ xc,
                                                  const float* __restrict__ w5t,
                                                  float* __restrict__ part) {
    int b = blockIdx.y, nt = blockIdx.x;
    int o4 = threadIdx.x;
    const float* xb = xc + ((size_t)b * NPTS + nt * 16) * XC_C;
    float4 acc[16];
#pragma unroll
    for (int i = 0; i < 16; i++) acc[i] = make_float4(0.f,0.f,0.f,0.f);
    for (int c = 0; c < 512; c++) {
        float4 w4 = ((const float4*)(w5t + (size_t)c * 1024))[o4];  // coalesced
#pragma unroll
        for (int nn = 0; nn < 16; nn++) {
            float xv = xb[(size_t)nn * XC_C + c];                   // uniform -> scalar path
            acc[nn].x = fmaf(w4.x, xv, acc[nn].x);
            acc[nn].y = fmaf(w4.y, xv, acc[nn].y);
            acc[nn].z = fmaf(w4.z, xv, acc[nn].z);
            acc[nn].w = fmaf(w4.w, xv, acc[nn].w);
        }
    }
    float4 m = acc[0];
#pragma unroll
    for (int nn = 1; nn < 16; nn++) {
        m.x = fmaxf(m.x, acc[nn].x); m.y = fmaxf(m.y, acc[nn].y);
        m.z = fmaxf(m.z, acc[nn].z); m.w = fmaxf(m.w, acc[nn].w);
    }
    ((float4*)(part + ((size_t)b * 64 + nt) * 1024))[o4] = m;
}

// ---- head: reduce partials -> gpool -> lin1/bn6/lrelu -> lin2/bn7/lrelu -> lin3 ----
__global__ __launch_bounds__(256) void head_k(const float* __restrict__ part,
        const float* __restrict__ l1w, const float* __restrict__ g6, const float* __restrict__ b6,
        const float* __restrict__ l2w, const float* __restrict__ l2b,
        const float* __restrict__ g7, const float* __restrict__ b7,
        const float* __restrict__ l3w, const float* __restrict__ l3b,
        float* __restrict__ out) {
    int b = blockIdx.x, t = threadIdx.x;
    __shared__ float gp[1024];
    __shared__ float y1[512];
    __shared__ float y2[256];
    const float* pb = part + (size_t)b * 64 * 1024;
    for (int o = t; o < 1024; o += 256) {
        float m = pb[o];
        for (int j = 1; j < 64; j++) m = fmaxf(m, pb[(size_t)j * 1024 + o]);
        gp[o] = m;
    }
    __syncthreads();
    for (int j = t; j < 512; j += 256) {
        const float4* wr = (const float4*)(l1w + (size_t)j * 1024);
        const float4* g4 = (const float4*)gp;
        float acc = 0.f;
        for (int c = 0; c < 256; c++) {
            float4 w = wr[c], x = g4[c];
            acc = fmaf(w.x,x.x, fmaf(w.y,x.y, fmaf(w.z,x.z, fmaf(w.w,x.w, acc))));
        }
        y1[j] = lrelu(fmaf(acc, g6[j] * BN_SC, b6[j]));
    }
    __syncthreads();
    {
        const float4* wr = (const float4*)(l2w + (size_t)t * 512);
        const float4* y4 = (const float4*)y1;
        float acc = l2b[t];
        for (int c = 0; c < 128; c++) {
            float4 w = wr[c], x = y4[c];
            acc = fmaf(w.x,x.x, fmaf(w.y,x.y, fmaf(w.z,x.z, fmaf(w.w,x.w, acc))));
        }
        y2[t] = lrelu(fmaf(acc, g7[t] * BN_SC, b7[t]));
    }
    __syncthreads();
    if (t < 40) {
        const float4* wr = (const float4*)(l3w + (size_t)t * 256);
        const float4* y4 = (const float4*)y2;
        float acc = l3b[t];
        for (int c = 0; c < 64; c++) {
            float4 w = wr[c], x = y4[c];
            acc = fmaf(w.x,x.x, fmaf(w.y,x.y, fmaf(w.z,x.z, fmaf(w.w,x.w, acc))));
        }
        out[b * 40 + t] = acc;
    }
}

extern "C" void kernel_launch(void* const* d_in, const int* in_sizes, int n_in,
                              void* d_out, int out_size, void* d_ws, size_t ws_size,
                              hipStream_t stream) {
    const float* x       = (const float*)d_in[0];
    const float* conv1_w = (const float*)d_in[1];
    const float* conv1_b = (const float*)d_in[2];
    const float* bn1_g   = (const float*)d_in[3];
    const float* bn1_b   = (const float*)d_in[4];
    const float* conv2_w = (const float*)d_in[5];
    const float* bn2_g   = (const float*)d_in[6];
    const float* bn2_b   = (const float*)d_in[7];
    const float* conv3_w = (const float*)d_in[8];
    const float* bn3_g   = (const float*)d_in[9];
    const float* bn3_b   = (const float*)d_in[10];
    const float* conv4_w = (const float*)d_in[11];
    const float* bn4_g   = (const float*)d_in[12];
    const float* bn4_b   = (const float*)d_in[13];
    const float* conv5_w = (const float*)d_in[14];
    const float* lin1_w  = (const float*)d_in[15];
    const float* bn6_g   = (const float*)d_in[16];
    const float* bn6_b   = (const float*)d_in[17];
    const float* lin2_w  = (const float*)d_in[18];
    const float* lin2_b  = (const float*)d_in[19];
    const float* bn7_g   = (const float*)d_in[20];
    const float* bn7_b   = (const float*)d_in[21];
    const float* lin3_w  = (const float*)d_in[22];
    const float* lin3_b  = (const float*)d_in[23];
    float* outp = (float*)d_out;

    // workspace layout (floats): total 10,657,792 f = 42.6 MB
    float* ws   = (float*)d_ws;
    float* xc   = ws;                          // (BN,512)          4,194,304
    int*   idxb = (int*)(ws + 4194304);        // (BN,20)             163,840
    float* nrm  = ws + 4194304 + 163840;       // (BN)                  8,192
    float* ft   = nrm + 8192;                  // (B,<=128,N)       1,048,576
    float* part = ft + 1048576;                // (B,64,1024)         524,288
    float* w5t  = part + 524288;               // (512,1024)          524,288
    float* Ht   = w5t + 524288;                // (BN,<=256)        2,097,152
    float* Ct   = Ht + 2097152;                // (BN,<=256)        2,097,152

    prep_k<<<BN/256, 256, 0, stream>>>(x, ft, nrm);

    // Stage 1: C=3 (coords), O=64, with conv bias
    knn_k<3><<<BN/8, 256, 0, stream>>>(ft, x, 3, nrm, idxb);
    hc_k<3, 64, true><<<BN/4, 64, 0, stream>>>(x, 3, conv1_w, conv1_b, Ht, Ct);
    gmax_k<64, true><<<BN, 64, 0, stream>>>(Ht, Ct, idxb, bn1_g, bn1_b, xc + 0, ft, nrm);

    // Stage 2: C=64 -> O=64
    knn_k<64><<<BN/8, 256, 0, stream>>>(ft, xc + 0, XC_C, nrm, idxb);
    hc_k<64, 64, false><<<BN/4, 64, 0, stream>>>(xc + 0, XC_C, conv2_w, nullptr, Ht, Ct);
    gmax_k<64, true><<<BN, 64, 0, stream>>>(Ht, Ct, idxb, bn2_g, bn2_b, xc + 64, ft, nrm);

    // Stage 3: C=64 -> O=128
    knn_k<64><<<BN/8, 256, 0, stream>>>(ft, xc + 64, XC_C, nrm, idxb);
    hc_k<64, 128, false><<<BN/4, 128, 0, stream>>>(xc + 64, XC_C, conv3_w, nullptr, Ht, Ct);
    gmax_k<128, true><<<BN, 128, 0, stream>>>(Ht, Ct, idxb, bn3_g, bn3_b, xc + 128, ft, nrm);

    // Stage 4: C=128 -> O=256 (no next knn)
    knn_k<128><<<BN/8, 256, 0, stream>>>(ft, xc + 128, XC_C, nrm, idxb);
    hc_k<128, 256, false><<<BN/4, 256, 0, stream>>>(xc + 128, XC_C, conv4_w, nullptr, Ht, Ct);
    gmax_k<256, false><<<BN, 256, 0, stream>>>(Ht, Ct, idxb, bn4_g, bn4_b, xc + 256, nullptr, nullptr);

    // conv5 + global max pool + head
    w5t_k<<<(512*1024)/256, 256, 0, stream>>>(conv5_w, w5t);
    conv5max_k<<<dim3(64, NB), 256, 0, stream>>>(xc, w5t, part);
    head_k<<<NB, 256, 0, stream>>>(part, lin1_w, bn6_g, bn6_b, lin2_w, lin2_b,
                                   bn7_g, bn7_b, lin3_w, lin3_b, outp);
}

// Round 6
// 656.981 us; speedup vs baseline: 1.3805x; 1.1591x over previous
//
#include <hip/hip_runtime.h>
#include <cmath>
#include <cstdint>
#include <cstddef>

#define NB 8
#define NPTS 1024
#define BN (NB*NPTS)
#define KNN 20
#define XC_C 512
#define BN_SC 0.99999500003749973f  // 1/sqrt(1+1e-5)

static __device__ __forceinline__ float lrelu(float z) { return z >= 0.f ? z : 0.01f * z; }

static __device__ __forceinline__ unsigned long long maxu64(unsigned long long a, unsigned long long b) {
    return a > b ? a : b;
}

// Interleaved DPP max step for TWO independent (lo,hi) u64 chains — same semantics as the
// R2-validated dpp_max, issued pairwise so the two dependent chains overlap.
// CTRL: row_ror:1/2/4/8 = 0x121/0x122/0x124/0x128, row_bcast15=0x142, row_bcast31=0x143.
// bound_ctrl=false + old=0 -> lanes with no source contribute 0 (= -inf sentinel).
template<int CTRL>
static __device__ __forceinline__ void dpp_max2(unsigned& loA, unsigned& hiA,
                                                unsigned& loB, unsigned& hiB) {
    unsigned tlA = (unsigned)__builtin_amdgcn_update_dpp(0, (int)loA, CTRL, 0xF, 0xF, false);
    unsigned thA = (unsigned)__builtin_amdgcn_update_dpp(0, (int)hiA, CTRL, 0xF, 0xF, false);
    unsigned tlB = (unsigned)__builtin_amdgcn_update_dpp(0, (int)loB, CTRL, 0xF, 0xF, false);
    unsigned thB = (unsigned)__builtin_amdgcn_update_dpp(0, (int)hiB, CTRL, 0xF, 0xF, false);
    unsigned long long a = ((unsigned long long)hiA << 32) | loA;
    unsigned long long b = ((unsigned long long)thA << 32) | tlA;
    if (b > a) { loA = tlA; hiA = thA; }
    unsigned long long c = ((unsigned long long)hiB << 32) | loB;
    unsigned long long d = ((unsigned long long)thB << 32) | tlB;
    if (d > c) { loB = tlB; hiB = thB; }
}

// Two interleaved wave-max chains; after the chain lane 63 holds each wave max (R2-validated pattern).
static __device__ __forceinline__ void wave_max_u64_x2(unsigned long long vA, unsigned long long vB,
                                                       unsigned long long& winA, unsigned long long& winB) {
    unsigned loA = (unsigned)vA, hiA = (unsigned)(vA >> 32);
    unsigned loB = (unsigned)vB, hiB = (unsigned)(vB >> 32);
    dpp_max2<0x121>(loA, hiA, loB, hiB);
    dpp_max2<0x122>(loA, hiA, loB, hiB);
    dpp_max2<0x124>(loA, hiA, loB, hiB);
    dpp_max2<0x128>(loA, hiA, loB, hiB);
    dpp_max2<0x142>(loA, hiA, loB, hiB);   // row_bcast15
    dpp_max2<0x143>(loA, hiA, loB, hiB);   // row_bcast31; lane63 = wave max
    unsigned wloA = (unsigned)__builtin_amdgcn_readlane((int)loA, 63);
    unsigned whiA = (unsigned)__builtin_amdgcn_readlane((int)hiA, 63);
    unsigned wloB = (unsigned)__builtin_amdgcn_readlane((int)loB, 63);
    unsigned whiB = (unsigned)__builtin_amdgcn_readlane((int)hiB, 63);
    winA = ((unsigned long long)whiA << 32) | wloA;
    winB = ((unsigned long long)whiB << 32) | wloB;
}

// ---- prep: x (B,N,3) -> ft (B,3,N) + norms ----
__global__ void prep_k(const float* __restrict__ x, float* __restrict__ ft, float* __restrict__ nrm) {
    int i = blockIdx.x * 256 + threadIdx.x;   // b*N+n
    if (i >= BN) return;
    int b = i >> 10, n = i & 1023;
    float a = x[3*i], c = x[3*i+1], d = x[3*i+2];
    float* fb = ft + (size_t)b * 3 * NPTS;
    fb[n] = a; fb[NPTS + n] = c; fb[2*NPTS + n] = d;
    nrm[i] = a*a + c*c + d*d;
}

// ---- fused knn: R2 semantics, TWO rows per wave (interleaved chains for ILP).
// Keys: hi = order-preserving u32 of (2*inner - xx[m]) (row-constant shift keeps jax order+ties),
//       lo = 1023-m  => u64-descending pop == (value desc, m asc) == jax top_k order.
// grid BN/8 blocks x 256 threads; wave w handles rows base+2w and base+2w+1.
template<int C>
__global__ __launch_bounds__(256) void knn_k(const float* __restrict__ ft,
                                             const float* __restrict__ frow, int frs,
                                             const float* __restrict__ nrm,
                                             int* __restrict__ idx) {
    int w = threadIdx.x >> 6;
    int lane = threadIdx.x & 63;
    int rA = blockIdx.x * 8 + 2 * w;
    int rB = rA + 1;
    int b = rA >> 10;                       // same batch for both rows (8 | 1024)
    const float* ftb = ft + (size_t)b * C * NPTS;

    float4 accA[4], accB[4];
#pragma unroll
    for (int j = 0; j < 4; j++) { accA[j] = make_float4(0.f,0.f,0.f,0.f); accB[j] = make_float4(0.f,0.f,0.f,0.f); }

    if constexpr ((C & 3) == 0) {
        const float4* crA = (const float4*)(frow + (size_t)rA * frs);
        const float4* crB = (const float4*)(frow + (size_t)rB * frs);
        for (int c4 = 0; c4 < C/4; c4++) {
            float4 ctA = crA[c4], ctB = crB[c4];
#pragma unroll
            for (int cc = 0; cc < 4; cc++) {
                float cA = (&ctA.x)[cc], cB = (&ctB.x)[cc];
                const float4* rm = (const float4*)(ftb + (size_t)(4*c4+cc) * NPTS);
#pragma unroll
                for (int j = 0; j < 4; j++) {
                    float4 v = rm[lane + 64*j];          // shared m-stream for both rows
                    accA[j].x = fmaf(cA, v.x, accA[j].x);
                    accA[j].y = fmaf(cA, v.y, accA[j].y);
                    accA[j].z = fmaf(cA, v.z, accA[j].z);
                    accA[j].w = fmaf(cA, v.w, accA[j].w);
                    accB[j].x = fmaf(cB, v.x, accB[j].x);
                    accB[j].y = fmaf(cB, v.y, accB[j].y);
                    accB[j].z = fmaf(cB, v.z, accB[j].z);
                    accB[j].w = fmaf(cB, v.w, accB[j].w);
                }
            }
        }
    } else {
        for (int c = 0; c < C; c++) {
            float cA = frow[(size_t)rA * frs + c];
            float cB = frow[(size_t)rB * frs + c];
            const float4* rm = (const float4*)(ftb + (size_t)c * NPTS);
#pragma unroll
            for (int j = 0; j < 4; j++) {
                float4 v = rm[lane + 64*j];
                accA[j].x = fmaf(cA, v.x, accA[j].x);
                accA[j].y = fmaf(cA, v.y, accA[j].y);
                accA[j].z = fmaf(cA, v.z, accA[j].z);
                accA[j].w = fmaf(cA, v.w, accA[j].w);
                accB[j].x = fmaf(cB, v.x, accB[j].x);
                accB[j].y = fmaf(cB, v.y, accB[j].y);
                accB[j].z = fmaf(cB, v.z, accB[j].z);
                accB[j].w = fmaf(cB, v.w, accB[j].w);
            }
        }
    }

    unsigned long long keyA[16], keyB[16];
    const float4* nm4 = (const float4*)(nrm + b * NPTS);
#pragma unroll
    for (int j = 0; j < 4; j++) {
        float4 nm = nm4[lane + 64*j];                    // shared for both rows
#pragma unroll
        for (int q = 0; q < 4; q++) {
            int m = 4*(lane + 64*j) + q;
            float fA = 2.f * (&accA[j].x)[q] - (&nm.x)[q];
            unsigned uA = __float_as_uint(fA);
            unsigned sA = (unsigned)((int)uA >> 31);
            uA ^= (sA | 0x80000000u);
            keyA[4*j+q] = ((unsigned long long)uA << 32) | (unsigned)(1023 - m);
            float fB = 2.f * (&accB[j].x)[q] - (&nm.x)[q];
            unsigned uB = __float_as_uint(fB);
            unsigned sB = (unsigned)((int)uB >> 31);
            uB ^= (sB | 0x80000000u);
            keyB[4*j+q] = ((unsigned long long)uB << 32) | (unsigned)(1023 - m);
        }
    }

    int mineA = 0, mineB = 0;
    for (int kk = 0; kk < KNN; kk++) {
        // balanced local max-trees (interleaved A/B for ILP)
        unsigned long long a01 = maxu64(keyA[0], keyA[1]),  b01 = maxu64(keyB[0], keyB[1]);
        unsigned long long a23 = maxu64(keyA[2], keyA[3]),  b23 = maxu64(keyB[2], keyB[3]);
        unsigned long long a45 = maxu64(keyA[4], keyA[5]),  b45 = maxu64(keyB[4], keyB[5]);
        unsigned long long a67 = maxu64(keyA[6], keyA[7]),  b67 = maxu64(keyB[6], keyB[7]);
        unsigned long long a89 = maxu64(keyA[8], keyA[9]),  b89 = maxu64(keyB[8], keyB[9]);
        unsigned long long aab = maxu64(keyA[10], keyA[11]), bab = maxu64(keyB[10], keyB[11]);
        unsigned long long acd = maxu64(keyA[12], keyA[13]), bcd = maxu64(keyB[12], keyB[13]);
        unsigned long long aef = maxu64(keyA[14], keyA[15]), bef = maxu64(keyB[14], keyB[15]);
        unsigned long long aq0 = maxu64(a01, a23), bq0 = maxu64(b01, b23);
        unsigned long long aq1 = maxu64(a45, a67), bq1 = maxu64(b45, b67);
        unsigned long long aq2 = maxu64(a89, aab), bq2 = maxu64(b89, bab);
        unsigned long long aq3 = maxu64(acd, aef), bq3 = maxu64(bcd, bef);
        unsigned long long bestA = maxu64(maxu64(aq0, aq1), maxu64(aq2, aq3));
        unsigned long long bestB = maxu64(maxu64(bq0, bq1), maxu64(bq2, bq3));
        unsigned long long winA, winB;
        wave_max_u64_x2(bestA, bestB, winA, winB);
        if (lane == kk) {
            mineA = 1023 - (int)(unsigned)winA;
            mineB = 1023 - (int)(unsigned)winB;
        }
        // invalidate winners (u64 keys unique per row; 0 unreachable => safe sentinel)
#pragma unroll
        for (int t = 0; t < 16; t++) {
            keyA[t] = (keyA[t] == winA) ? 0ull : keyA[t];
            keyB[t] = (keyB[t] == winB) ? 0ull : keyB[t];
        }
    }
    if (lane < KNN) {
        idx[rA * KNN + lane] = mineA;
        idx[rB * KNN + lane] = mineB;
    }
}

// ---- H/Ct GEMM: Ht[n,o]=F.w1; Ct[n,o]=F.w2 - Ht + bias ----
// grid BN/4, block O; 4 rows per block for w-reuse.
template<int C, int O, bool HASB>
__global__ void hc_k(const float* __restrict__ F, int FS,
                     const float* __restrict__ w, const float* __restrict__ bias,
                     float* __restrict__ Ht, float* __restrict__ Ct) {
    int r0 = blockIdx.x * 4;
    int o = threadIdx.x;
    const float* wr = w + (size_t)o * (2*C);
    float h[4] = {0,0,0,0}, a2[4] = {0,0,0,0};
    if constexpr ((C & 3) == 0) {
        const float4* w1 = (const float4*)wr;
        const float4* w2 = (const float4*)(wr + C);
#pragma unroll 4
        for (int c4 = 0; c4 < C/4; c4++) {
            float4 wa = w1[c4], wb = w2[c4];
#pragma unroll
            for (int nn = 0; nn < 4; nn++) {
                float4 f = *(const float4*)(F + (size_t)(r0+nn)*FS + 4*c4);  // broadcast
                h[nn]  = fmaf(wa.x,f.x, fmaf(wa.y,f.y, fmaf(wa.z,f.z, fmaf(wa.w,f.w, h[nn]))));
                a2[nn] = fmaf(wb.x,f.x, fmaf(wb.y,f.y, fmaf(wb.z,f.z, fmaf(wb.w,f.w, a2[nn]))));
            }
        }
    } else {
        for (int c = 0; c < C; c++) {
            float wa = wr[c], wb = wr[C+c];
#pragma unroll
            for (int nn = 0; nn < 4; nn++) {
                float f = F[(size_t)(r0+nn)*FS + c];
                h[nn]  = fmaf(wa, f, h[nn]);
                a2[nn] = fmaf(wb, f, a2[nn]);
            }
        }
    }
    float bs = 0.f;
    if constexpr (HASB) bs = bias[o];
#pragma unroll
    for (int nn = 0; nn < 4; nn++) {
        size_t ro = (size_t)(r0+nn)*O + o;
        Ht[ro] = h[nn];
        Ct[ro] = a2[nn] - h[nn] + bs;
    }
}

// ---- gather + max_k + bn + lrelu; optional transposed-feature + norms for next knn ----
template<int O, bool WFT>
__global__ void gmax_k(const float* __restrict__ Ht, const float* __restrict__ Ct,
                       const int* __restrict__ idx,
                       const float* __restrict__ g, const float* __restrict__ bb,
                       float* __restrict__ xcs, float* __restrict__ ft, float* __restrict__ nrm) {
    int r = blockIdx.x;
    int b = r >> 10, n = r & 1023;
    int o = threadIdx.x;
    const int* id = idx + r * KNN;
    float vmax = -INFINITY, vmin = INFINITY;
    const float* hb = Ht + (size_t)b * NPTS * O + o;
#pragma unroll 4
    for (int k = 0; k < KNN; k++) {
        int m = id[k];                 // broadcast
        float v = hb[(size_t)m * O];   // coalesced across o
        vmax = fmaxf(vmax, v); vmin = fminf(vmin, v);
    }
    float ct = Ct[(size_t)r * O + o];
    float s = g[o] * BN_SC;
    float pre = (s >= 0.f ? vmax : vmin) + ct;
    float out = lrelu(fmaf(s, pre, bb[o]));
    xcs[(size_t)r * XC_C + o] = out;
    if constexpr (WFT) {
        ft[((size_t)b * O + o) * NPTS + n] = out;
        float sq = out * out;
#pragma unroll
        for (int off = 32; off > 0; off >>= 1) sq += __shfl_xor(sq, off);
        __shared__ float red[O/64 > 0 ? O/64 : 1];
        if ((o & 63) == 0) red[o >> 6] = sq;
        __syncthreads();
        if (o == 0) {
            float t = 0.f;
#pragma unroll
            for (int i = 0; i < O/64; i++) t += red[i];
            nrm[r] = t;
        }
    }
}

// ---- w5 transpose (1024,512) -> (512,1024) for coalesced o-loads ----
__global__ void w5t_k(const float* __restrict__ w5, float* __restrict__ w5t) {
    int i = blockIdx.x * 256 + threadIdx.x;   // c*1024+o
    int c = i >> 10, o = i & 1023;
    w5t[i] = w5[(size_t)o * 512 + c];
}

// ---- conv5 + partial max over n: grid (64 ntiles, B), block 256; thread = 4 o, 16 n ----
__global__ __launch_bounds__(256) void conv5max_k(const float* __restrict__ xc,
                                                  const float* __restrict__ w5t,
                                                  float* __restrict__ part) {
    int b = blockIdx.y, nt = blockIdx.x;
    int o4 = threadIdx.x;
    const float* xb = xc + ((size_t)b * NPTS + nt * 16) * XC_C;
    float4 acc[16];
#pragma unroll
    for (int i = 0; i < 16; i++) acc[i] = make_float4(0.f,0.f,0.f,0.f);
    for (int c = 0; c < 512; c++) {
        float4 w4 = ((const float4*)(w5t + (size_t)c * 1024))[o4];  // coalesced
#pragma unroll
        for (int nn = 0; nn < 16; nn++) {
            float xv = xb[(size_t)nn * XC_C + c];                   // uniform -> scalar path
            acc[nn].x = fmaf(w4.x, xv, acc[nn].x);
            acc[nn].y = fmaf(w4.y, xv, acc[nn].y);
            acc[nn].z = fmaf(w4.z, xv, acc[nn].z);
            acc[nn].w = fmaf(w4.w, xv, acc[nn].w);
        }
    }
    float4 m = acc[0];
#pragma unroll
    for (int nn = 1; nn < 16; nn++) {
        m.x = fmaxf(m.x, acc[nn].x); m.y = fmaxf(m.y, acc[nn].y);
        m.z = fmaxf(m.z, acc[nn].z); m.w = fmaxf(m.w, acc[nn].w);
    }
    ((float4*)(part + ((size_t)b * 64 + nt) * 1024))[o4] = m;
}

// ---- global max pool: gp[b,o] = max_j part[b,j,o] ----
__global__ void gpool_k(const float* __restrict__ part, float* __restrict__ gp) {
    int i = blockIdx.x * 256 + threadIdx.x;   // b*1024+o
    int b = i >> 10, o = i & 1023;
    const float* pb = part + (size_t)b * 64 * 1024 + o;
    float m = pb[0];
#pragma unroll 4
    for (int j = 1; j < 64; j++) m = fmaxf(m, pb[(size_t)j * 1024]);
    gp[i] = m;
}

// ---- linear layer, one wave per output dot: Y[b,o] = act(dot(X[b], W[o]) (+bias)) ----
// wave id = o*NB + b so the 8 batches sharing a weight row are adjacent (L2 reuse).
template<int C, bool HASBIAS, bool ACT>
__global__ __launch_bounds__(256) void lin_k(const float* __restrict__ X, int xs,
                                             const float* __restrict__ W,
                                             const float* __restrict__ bias,
                                             const float* __restrict__ g, const float* __restrict__ bb,
                                             float* __restrict__ Y, int ys) {
    int wid = (blockIdx.x * 256 + threadIdx.x) >> 6;
    int lane = threadIdx.x & 63;
    int o = wid >> 3;          // NB = 8
    int b = wid & 7;
    const float4* wr = (const float4*)(W + (size_t)o * C);
    const float4* xr = (const float4*)(X + (size_t)b * xs);
    float acc = 0.f;
#pragma unroll
    for (int i = 0; i < C/256; i++) {
        float4 w = wr[lane + 64*i];
        float4 xv = xr[lane + 64*i];
        acc = fmaf(w.x,xv.x, fmaf(w.y,xv.y, fmaf(w.z,xv.z, fmaf(w.w,xv.w, acc))));
    }
#pragma unroll
    for (int off = 32; off > 0; off >>= 1) acc += __shfl_xor(acc, off);
    if (lane == 0) {
        if constexpr (HASBIAS) acc += bias[o];
        if constexpr (ACT) acc = lrelu(fmaf(acc, g[o] * BN_SC, bb[o]));
        Y[(size_t)b * ys + o] = acc;
    }
}

extern "C" void kernel_launch(void* const* d_in, const int* in_sizes, int n_in,
                              void* d_out, int out_size, void* d_ws, size_t ws_size,
                              hipStream_t stream) {
    const float* x       = (const float*)d_in[0];
    const float* conv1_w = (const float*)d_in[1];
    const float* conv1_b = (const float*)d_in[2];
    const float* bn1_g   = (const float*)d_in[3];
    const float* bn1_b   = (const float*)d_in[4];
    const float* conv2_w = (const float*)d_in[5];
    const float* bn2_g   = (const float*)d_in[6];
    const float* bn2_b   = (const float*)d_in[7];
    const float* conv3_w = (const float*)d_in[8];
    const float* bn3_g   = (const float*)d_in[9];
    const float* bn3_b   = (const float*)d_in[10];
    const float* conv4_w = (const float*)d_in[11];
    const float* bn4_g   = (const float*)d_in[12];
    const float* bn4_b   = (const float*)d_in[13];
    const float* conv5_w = (const float*)d_in[14];
    const float* lin1_w  = (const float*)d_in[15];
    const float* bn6_g   = (const float*)d_in[16];
    const float* bn6_b   = (const float*)d_in[17];
    const float* lin2_w  = (const float*)d_in[18];
    const float* lin2_b  = (const float*)d_in[19];
    const float* bn7_g   = (const float*)d_in[20];
    const float* bn7_b   = (const float*)d_in[21];
    const float* lin3_w  = (const float*)d_in[22];
    const float* lin3_b  = (const float*)d_in[23];
    float* outp = (float*)d_out;

    // workspace layout (floats): total 10,657,792 f = 42.6 MB
    float* ws   = (float*)d_ws;
    float* xc   = ws;                          // (BN,512)          4,194,304
    int*   idxb = (int*)(ws + 4194304);        // (BN,20)             163,840
    float* nrm  = ws + 4194304 + 163840;       // (BN)                  8,192
    float* ft   = nrm + 8192;                  // (B,<=128,N)       1,048,576
    float* part = ft + 1048576;                // (B,64,1024)         524,288
    float* w5t  = part + 524288;               // (512,1024)          524,288
    float* Ht   = w5t + 524288;                // (BN,<=256)        2,097,152
    float* Ct   = Ht + 2097152;                // (BN,<=256)        2,097,152
    // head scratch aliases ft (dead after the last knn_k):
    float* gp   = ft;                          // (8,1024)
    float* y1   = ft + 8192;                   // (8,512)
    float* y2   = ft + 8192 + 4096;            // (8,256)

    prep_k<<<BN/256, 256, 0, stream>>>(x, ft, nrm);

    // Stage 1: C=3 (coords), O=64, with conv bias
    knn_k<3><<<BN/8, 256, 0, stream>>>(ft, x, 3, nrm, idxb);
    hc_k<3, 64, true><<<BN/4, 64, 0, stream>>>(x, 3, conv1_w, conv1_b, Ht, Ct);
    gmax_k<64, true><<<BN, 64, 0, stream>>>(Ht, Ct, idxb, bn1_g, bn1_b, xc + 0, ft, nrm);

    // Stage 2: C=64 -> O=64
    knn_k<64><<<BN/8, 256, 0, stream>>>(ft, xc + 0, XC_C, nrm, idxb);
    hc_k<64, 64, false><<<BN/4, 64, 0, stream>>>(xc + 0, XC_C, conv2_w, nullptr, Ht, Ct);
    gmax_k<64, true><<<BN, 64, 0, stream>>>(Ht, Ct, idxb, bn2_g, bn2_b, xc + 64, ft, nrm);

    // Stage 3: C=64 -> O=128
    knn_k<64><<<BN/8, 256, 0, stream>>>(ft, xc + 64, XC_C, nrm, idxb);
    hc_k<64, 128, false><<<BN/4, 128, 0, stream>>>(xc + 64, XC_C, conv3_w, nullptr, Ht, Ct);
    gmax_k<128, true><<<BN, 128, 0, stream>>>(Ht, Ct, idxb, bn3_g, bn3_b, xc + 128, ft, nrm);

    // Stage 4: C=128 -> O=256 (no next knn)
    knn_k<128><<<BN/8, 256, 0, stream>>>(ft, xc + 128, XC_C, nrm, idxb);
    hc_k<128, 256, false><<<BN/4, 256, 0, stream>>>(xc + 128, XC_C, conv4_w, nullptr, Ht, Ct);
    gmax_k<256, false><<<BN, 256, 0, stream>>>(Ht, Ct, idxb, bn4_g, bn4_b, xc + 256, nullptr, nullptr);

    // conv5 + global max pool + parallel head
    w5t_k<<<(512*1024)/256, 256, 0, stream>>>(conv5_w, w5t);
    conv5max_k<<<dim3(64, NB), 256, 0, stream>>>(xc, w5t, part);
    gpool_k<<<NB*1024/256, 256, 0, stream>>>(part, gp);
    lin_k<1024, false, true><<<NB*512/4, 256, 0, stream>>>(gp, 1024, lin1_w, nullptr, bn6_g, bn6_b, y1, 512);
    lin_k<512,  true,  true><<<NB*256/4, 256, 0, stream>>>(y1, 512, lin2_w, lin2_b, bn7_g, bn7_b, y2, 256);
    lin_k<256,  true, false><<<NB*40/4,  256, 0, stream>>>(y2, 256, lin3_w, lin3_b, nullptr, nullptr, outp, 40);
}